// Round 8
// baseline (243.990 us; speedup 1.0000x reference)
//
#include <hip/hip_runtime.h>
#include <hip/hip_bf16.h>
#include <math.h>

#define B_N 8192
#define D_DIM 1024
#define NWORDS 128   // u64 words per mask row
#define NBLK 1056    // (32 diag + 496 off-diag supertiles) * 2 half-blocks

using bf16 = __hip_bfloat16;
typedef float f32x4 __attribute__((ext_vector_type(4)));
typedef __bf16 bf16x8 __attribute__((ext_vector_type(8)));

// ws layout:
//   [0, 16MB)                : Xn bf16 [8192][1024]
//   [16MB, 24MB)             : maskbits u64 [8192][128]
//   red = 24MB:
//     red + 0      .. 32KB   : S[8192]  f32  (sum exp(sim-10), j != i)  [atomic, zeroed]
//     red + 32KB   .. 64KB   : P[8192]  f32  (popcount of mask row)     [written by pack]
//     red + 64KB   + 4       : flag u32  (mask-dtype detection)         [atomic, zeroed]
//     red + 64KB+256 ..      : Mpart[1056] f32 (per-block sum mask*sim) [written by sim]

__global__ void detect_mask_kernel(const unsigned* __restrict__ m, unsigned* __restrict__ flag) {
    unsigned c = 0;
    for (int i = blockIdx.x * blockDim.x + threadIdx.x; i < 262144;
         i += gridDim.x * blockDim.x) {
        c += (m[i] > 1u) ? 1u : 0u;
    }
    for (int s = 1; s < 64; s <<= 1) c += __shfl_xor(c, s, 64);
    if ((threadIdx.x & 63) == 0 && c) atomicAdd(flag, c);
}

// One thread per 64-bit output word (64 mask elements). Grid 4096 x 256.
__global__ void pack_mask_kernel(const unsigned char* __restrict__ m8,
                                 const int* __restrict__ m32,
                                 const unsigned* __restrict__ flag,
                                 unsigned long long* __restrict__ bits,
                                 float* __restrict__ P) {
    const bool is_u8 = (*flag != 0u);
    int tid = threadIdx.x;
    size_t w = (size_t)blockIdx.x * 256 + tid;
    unsigned long long word = 0;
    if (is_u8) {
        const uint4* src = (const uint4*)(m8 + w * 64);
#pragma unroll
        for (int q = 0; q < 4; ++q) {
            uint4 v = src[q];
            unsigned cs[4] = {v.x, v.y, v.z, v.w};
#pragma unroll
            for (int c = 0; c < 4; ++c) {
                unsigned u = ((cs[c] & 0x7F7F7F7Fu) + 0x7F7F7F7Fu) | cs[c];
                u &= 0x80808080u;
                unsigned nib = ((u >> 7) & 1u) | ((u >> 14) & 2u) | ((u >> 21) & 4u) | ((u >> 28) & 8u);
                word |= (unsigned long long)nib << ((q * 4 + c) * 4);
            }
        }
    } else {
        const uint4* src = (const uint4*)(m32 + w * 64);
#pragma unroll
        for (int q = 0; q < 16; ++q) {
            uint4 v = src[q];
            unsigned nib = (unsigned)(v.x != 0) | ((unsigned)(v.y != 0) << 1) |
                           ((unsigned)(v.z != 0) << 2) | ((unsigned)(v.w != 0) << 3);
            word |= (unsigned long long)nib << (q * 4);
        }
    }
    bits[w] = word;
    float pc = (float)__popcll(word);
    for (int s = 1; s < 64; s <<= 1) pc += __shfl_xor(pc, s, 64);
    __shared__ float wsum[4];
    if ((tid & 63) == 0) wsum[tid >> 6] = pc;
    __syncthreads();
    if (tid == 0)   P[blockIdx.x * 2]     = wsum[0] + wsum[1];
    if (tid == 128) P[blockIdx.x * 2 + 1] = wsum[2] + wsum[3];
}

__global__ void normalize_kernel(const float* __restrict__ emb, bf16* __restrict__ xn) {
    int row = blockIdx.x;
    int t = threadIdx.x;  // 256 threads, 4 floats each
    const float4* src = (const float4*)(emb + (size_t)row * D_DIM);
    float4 v = src[t];
    float ss = v.x * v.x + v.y * v.y + v.z * v.z + v.w * v.w;
    for (int s = 1; s < 64; s <<= 1) ss += __shfl_xor(ss, s, 64);
    __shared__ float wss[4];
    if ((t & 63) == 0) wss[t >> 6] = ss;
    __syncthreads();
    float tot = wss[0] + wss[1] + wss[2] + wss[3];
    float scale = 1.0f / fmaxf(sqrtf(tot), 1e-12f);
    ushort4 o;
    o.x = __builtin_bit_cast(unsigned short, __float2bfloat16(v.x * scale));
    o.y = __builtin_bit_cast(unsigned short, __float2bfloat16(v.y * scale));
    o.z = __builtin_bit_cast(unsigned short, __float2bfloat16(v.z * scale));
    o.w = __builtin_bit_cast(unsigned short, __float2bfloat16(v.w * scale));
    *reinterpret_cast<ushort4*>(xn + (size_t)row * D_DIM + t * 4) = o;
}

// 256x128 block tile (2 blocks per 256x256 supertile), BK=64, 512 threads,
// 8 waves (4M x 2N), per-wave 64x64 = 4x4 frags of 16x16x32.
// K-loop: 3-buffer LDS rotation with counted vmcnt (T3+T4): iter t computes
// K-tile t from bank t%3 while staging K-tile t+2 into bank (t+2)%3; iter
// ends with s_waitcnt vmcnt(6) (guarantees PREVIOUS iter's 6 loads = next
// tile landed; this iter's 6 stay in flight) + raw s_barrier (no vmcnt(0)
// drain) + sched_barrier(0) (pin: no ds_read/stage crosses the boundary).
// R7's LDS XOR swizzle carried over (chunk ^= row&7, pre-swizzled source).
__global__ __launch_bounds__(512, 2) void sim_kernel(
    const bf16* __restrict__ xn,
    const unsigned long long* __restrict__ mbits,
    float* __restrict__ S, float* __restrict__ Mpart)
{
    __shared__ bf16 SL[3 * 24576];  // bank: A[256*64] @0, B[128*64] @16384
    __shared__ float Mred[8];

    // XCD-aware bijective swizzle (1056 = 8 * 132)
    int b0 = blockIdx.x;
    int lin = (b0 & 7) * 132 + (b0 >> 3);
    int s = lin >> 1, h = lin & 1;
    int by, bx;
    bool diagst;
    if (s < 32) {
        by = bx = s; diagst = true;
    } else {
        int j = s - 32;  // [0, 496)
        int p = (int)((sqrt((double)(8 * j + 1)) + 1.0) * 0.5);
        while (p * (p - 1) / 2 > j) --p;
        while ((p + 1) * p / 2 <= j) ++p;
        by = j - p * (p - 1) / 2; bx = p;  // by < bx
        diagst = false;
    }

    int tid = threadIdx.x;
    int w = tid >> 6, lane = tid & 63;
    int wm = w >> 1, wn = w & 1;      // 4M x 2N waves
    int l15 = lane & 15, lg = lane >> 4;

    f32x4 acc[4][4];
#pragma unroll
    for (int i = 0; i < 4; i++)
#pragma unroll
        for (int j = 0; j < 4; j++) acc[i][j] = {0.f, 0.f, 0.f, 0.f};

    int arow0 = by << 8;                    // 256 rows
    int bcol0 = (bx << 8) + (h << 7);       // 128 cols

    // staging geometry: round i: e = i*512 + tid; row = i*64 + (tid>>3),
    // dest slot = tid&7 (linear), source chunk = slot ^ (row&7).
    int csrc = (((tid & 7) ^ ((tid >> 3) & 7)) << 3);  // element offset
    int rl = tid >> 3;                                  // row within round
    int wub = tid & ~63;                                // wave-uniform e part
    int xr = l15 & 7;                                   // read-side XOR

#define STAGE(bk, kt)                                                                       \
    do {                                                                                    \
        bf16* Ad = SL + (bk) * 24576;                                                       \
        bf16* Bd = Ad + 16384;                                                              \
        _Pragma("unroll") for (int i = 0; i < 4; ++i) {                                     \
            const bf16* g = xn + (size_t)(arow0 + i * 64 + rl) * D_DIM + (kt) * 64 + csrc;  \
            char* l = (char*)Ad + (size_t)(i * 512 + wub) * 16;                             \
            __builtin_amdgcn_global_load_lds((const __attribute__((address_space(1))) void*)g, \
                                             (__attribute__((address_space(3))) void*)l, 16, 0, 0); \
        }                                                                                   \
        _Pragma("unroll") for (int i = 0; i < 2; ++i) {                                     \
            const bf16* g = xn + (size_t)(bcol0 + i * 64 + rl) * D_DIM + (kt) * 64 + csrc;  \
            char* l = (char*)Bd + (size_t)(i * 512 + wub) * 16;                             \
            __builtin_amdgcn_global_load_lds((const __attribute__((address_space(1))) void*)g, \
                                             (__attribute__((address_space(3))) void*)l, 16, 0, 0); \
        }                                                                                   \
    } while (0)

    // prologue: K0 -> bank0, K1 -> bank1; wait K0 only (6 newest may fly)
    STAGE(0, 0);
    STAGE(1, 1);
    asm volatile("s_waitcnt vmcnt(6)" ::: "memory");
    __builtin_amdgcn_s_barrier();
    __builtin_amdgcn_sched_barrier(0);

    for (int t = 0; t < 16; ++t) {
        bf16* Ab = SL + (t % 3) * 24576;
        bf16* Bb = Ab + 16384;
        if (t < 14) STAGE((t + 2) % 3, t + 2);

        bf16x8 a[4][2], b[4][2];
#pragma unroll
        for (int f = 0; f < 4; ++f)
#pragma unroll
            for (int kk = 0; kk < 2; ++kk) {
                int ca = (((kk << 2) | lg) ^ xr) << 3;
                b[f][kk] = *reinterpret_cast<const bf16x8*>(Bb + (wn * 64 + f * 16 + l15) * 64 + ca);
                a[f][kk] = *reinterpret_cast<const bf16x8*>(Ab + (wm * 64 + f * 16 + l15) * 64 + ca);
            }
#pragma unroll
        for (int kk = 0; kk < 2; ++kk)
#pragma unroll
            for (int fm = 0; fm < 4; ++fm)
#pragma unroll
                for (int fn = 0; fn < 4; ++fn)
                    acc[fm][fn] = __builtin_amdgcn_mfma_f32_16x16x32_bf16(a[fm][kk], b[fn][kk], acc[fm][fn], 0, 0, 0);

        if (t < 15) {
            if (t < 14) asm volatile("s_waitcnt vmcnt(6)" ::: "memory");
            else        asm volatile("s_waitcnt vmcnt(0)" ::: "memory");
            __builtin_amdgcn_s_barrier();
            __builtin_amdgcn_sched_barrier(0);
        }
    }
#undef STAGE

    // ---- Epilogue ----
    // C/D layout: col = l15, row = lg*4 + reg (within 16x16 frag).
    // Uniform keep-predicate: count ordered pair (gr,gc) iff gr<gc; its
    // transpose (gc,gr) is credited via the col-side with mask[gc][gr].
    // Off-diag supertiles always have gr<gc.
    float colE[4] = {0.f, 0.f, 0.f, 0.f};
    unsigned long long wcol[4];
#pragma unroll
    for (int fn = 0; fn < 4; ++fn) {
        int gc = bcol0 + wn * 64 + fn * 16 + l15;
        wcol[fn] = mbits[(size_t)gc * NWORDS + by * 4 + wm];
    }

    float Mloc = 0.f;
#pragma unroll
    for (int fm = 0; fm < 4; ++fm) {
#pragma unroll
        for (int reg = 0; reg < 4; ++reg) {
            int lr = fm * 16 + lg * 4 + reg;          // row within wave strip
            int gr = arow0 + wm * 64 + lr;
            unsigned long long wrow = mbits[(size_t)gr * NWORDS + bx * 4 + h * 2 + wn];
            float E = 0.f;
#pragma unroll
            for (int fn = 0; fn < 4; ++fn) {
                int gc = bcol0 + wn * 64 + fn * 16 + l15;
                float sim = acc[fm][fn][reg] * 10.0f;
                bool keep = !diagst || (gr < gc);
                float e = keep ? __expf(sim - 10.0f) : 0.f;
                E += e;
                colE[fn] += e;
                if (keep) {
                    if ((wrow >> (fn * 16 + l15)) & 1ull) Mloc += sim;
                    if ((wcol[fn] >> lr) & 1ull) Mloc += sim;
                }
            }
            E += __shfl_xor(E, 1, 64);
            E += __shfl_xor(E, 2, 64);
            E += __shfl_xor(E, 4, 64);
            E += __shfl_xor(E, 8, 64);
            if (l15 == 0) atomicAdd(&S[gr], E);
        }
    }

#pragma unroll
    for (int fn = 0; fn < 4; ++fn) {
        float E = colE[fn];
        E += __shfl_xor(E, 16, 64);
        E += __shfl_xor(E, 32, 64);
        if (lg == 0) atomicAdd(&S[bcol0 + wn * 64 + fn * 16 + l15], E);
    }

    for (int s2 = 1; s2 < 64; s2 <<= 1) Mloc += __shfl_xor(Mloc, s2, 64);
    if (lane == 0) Mred[w] = Mloc;
    __syncthreads();
    if (tid == 0) {
        float m = 0.f;
        for (int i = 0; i < 8; ++i) m += Mred[i];
        Mpart[b0] = m;
    }
}

__global__ void finalize_kernel(const float* __restrict__ S, const float* __restrict__ P,
                                const float* __restrict__ Mpart, float* __restrict__ out) {
    int t = threadIdx.x;  // 1024
    double a = 0.0;
    for (int i = t; i < B_N; i += 1024) {
        float lse = 10.0f + logf(S[i]);
        a += (double)P[i] * (double)lse;
    }
    for (int i = t; i < NBLK; i += 1024) a -= (double)Mpart[i];
    for (int s = 1; s < 64; s <<= 1) a += __shfl_xor(a, s, 64);
    __shared__ double sh[16];
    if ((t & 63) == 0) sh[t >> 6] = a;
    __syncthreads();
    if (t == 0) {
        double tot = 0.0;
        for (int i = 0; i < 16; ++i) tot += sh[i];
        out[0] = (float)(tot / (double)B_N);
    }
}

extern "C" void kernel_launch(void* const* d_in, const int* in_sizes, int n_in,
                              void* d_out, int out_size, void* d_ws, size_t ws_size,
                              hipStream_t stream) {
    const float* emb = (const float*)d_in[0];
    const void* mask = d_in[1];
    char* ws = (char*)d_ws;
    bf16* xn = (bf16*)ws;
    const size_t XN_BYTES = (size_t)B_N * D_DIM * 2;              // 16MB
    unsigned long long* mbits = (unsigned long long*)(ws + XN_BYTES);
    const size_t MB_BYTES = (size_t)B_N * NWORDS * 8;             // 8MB
    char* red = ws + XN_BYTES + MB_BYTES;
    float* S = (float*)red;
    float* P = (float*)(red + 32768);
    unsigned* flag = (unsigned*)(red + 65536 + 4);
    float* Mpart = (float*)(red + 65536 + 256);

    hipMemsetAsync(red, 0, 65536 + 16, stream);
    detect_mask_kernel<<<64, 256, 0, stream>>>((const unsigned*)mask, flag);
    pack_mask_kernel<<<4096, 256, 0, stream>>>((const unsigned char*)mask, (const int*)mask,
                                               flag, mbits, P);
    normalize_kernel<<<B_N, 256, 0, stream>>>(emb, xn);
    sim_kernel<<<NBLK, 512, 0, stream>>>(xn, mbits, S, Mpart);
    finalize_kernel<<<1, 1024, 0, stream>>>(S, P, Mpart, (float*)d_out);
}